// Round 12
// baseline (901.409 us; speedup 1.0000x reference)
//
#include <hip/hip_runtime.h>
#include <hip/hip_bf16.h>
#include <math.h>

#define N_NODES 50000
#define N_EDGES 800000
#define C 64
#define EPS_F 1.000001f

// Append-bucket store (round-11 lesson: ANY scatter of 4B records into a
// >25MB slab region pays ~10x HBM write amplification regardless of
// partition geometry — so append, never scatter).
// Bucket key = (conv, 64-node target range, sub); sub = blockIdx&7 thins
// same-line interleave. Records append via atomic cursor -> consecutive
// addresses -> lines fill in temporal order. Overflow cascades to next sub
// (gather reads all subs -> exact). Capacity: records per (range,conv) ~
// Binomial(E, 64/N) = 1024 +/- 32; per sub ~128 +/- 12; CAPB=192 >> safe.
#define RANGE 64
#define NRANGE ((N_NODES + RANGE - 1) / RANGE)    // 782
#define NSUB 8
#define NBKT (2 * NRANGE * NSUB)                  // 12512 buckets
#define CAPB 192                                  // rec = 12512*192*8B = 19.2 MB
#define LDS_STRIDE 66                             // bank-spread for ds_add

#define NPRE ((N_NODES + 31) / 32)   // 1563 blocks, 32 rows each
// Fused K1 geometry: groups of 8; role by (b>>3)%5: 4 fill-groups : 1 pre.
#define NGRP8 980
#define NK1 (NGRP8 * 8)              // 7840 blocks: 6272 fill + 1568 pre

typedef __attribute__((ext_vector_type(8))) unsigned short u16x8;

// float <-> bf16 bits (round-to-nearest-even)
__device__ __forceinline__ unsigned short f2bf(float f) {
    unsigned u = __float_as_uint(f);
    return (unsigned short)((u + 0x7FFFu + ((u >> 16) & 1u)) >> 16);
}
__device__ __forceinline__ float bf2f(unsigned short b) {
    return __uint_as_float(((unsigned)b) << 16);
}

// ---------------------------------------------------------------------------
// Kernel 0: attention scalars via the wa-trick + zero cnt[] (50 KB, trivial).
//   s_src = (x @ W) @ a_src = x @ (W @ a_src)
// ---------------------------------------------------------------------------
__global__ __launch_bounds__(256) void s_kernel(
    const float* __restrict__ x,
    const float* __restrict__ w_l, const float* __restrict__ a_l,
    const float* __restrict__ w_u, const float* __restrict__ a_u,
    float* __restrict__ ssl, float* __restrict__ stl,
    float* __restrict__ ssu, float* __restrict__ stu,
    int* __restrict__ cnt)
{
    const int b = blockIdx.x;
    const int t = threadIdx.x;

    const int gz = b * 256 + t;
    if (gz < NBKT + 8) cnt[gz] = 0;

    __shared__ float wa[4 * C];      // [l_src | l_tgt | u_src | u_tgt]
    {
        const int v = t >> 6;
        const int k = t & 63;
        const float* __restrict__ w = (v < 2) ? w_l : w_u;
        const float* __restrict__ a = (v < 2) ? a_l : a_u;
        const int ao = (v & 1) * C;
        float acc = 0.f;
#pragma unroll 16
        for (int o = 0; o < C; ++o)
            acc = fmaf(w[k * C + o], a[ao + o], acc);
        wa[v * C + k] = acc;
    }
    __syncthreads();

    const int lane = t & 63;
    const int wv = t >> 6;
    const int row0 = b * 32 + wv * 8;
    if (row0 >= N_NODES) return;

    const float wls = wa[lane], wlt = wa[C + lane];
    const float wus = wa[2 * C + lane], wut = wa[3 * C + lane];

#pragma unroll
    for (int r = 0; r < 8; ++r) {
        const int row = row0 + r;
        if (row >= N_NODES) break;
        const float xv = x[row * C + lane];
        float psl = xv * wls, ptl = xv * wlt;
        float psu = xv * wus, ptu = xv * wut;
#pragma unroll
        for (int o = 32; o >= 1; o >>= 1) {
            psl += __shfl_xor(psl, o);
            ptl += __shfl_xor(ptl, o);
            psu += __shfl_xor(psu, o);
            ptu += __shfl_xor(ptu, o);
        }
        if (lane == 0) {
            ssl[row] = psl; stl[row] = ptl;
            ssu[row] = psu; stu[row] = ptu;
        }
    }
}

// ---------------------------------------------------------------------------
// Kernel 1 (fused): GEMM precompute + append-bucket fill (no grid barrier).
// Fill: alpha = elu(s_src[j]+s_tgt[i])*val; append {j|alpha, i&63} to
// bucket (conv, i>>6, sub); cascade subs on overflow.
// Pre: 8 rows/wave, wave-uniform row ptrs -> scalar x loads.
// ---------------------------------------------------------------------------
__global__ __launch_bounds__(256) void gemm_fill_kernel(
    const float* __restrict__ x,
    const float* __restrict__ w_l, const float* __restrict__ w_u,
    const float* __restrict__ w_lin,
    const int* __restrict__ lidx, const float* __restrict__ lval,
    const int* __restrict__ uidx, const float* __restrict__ uval,
    const float* __restrict__ ssl, const float* __restrict__ stl,
    const float* __restrict__ ssu, const float* __restrict__ stu,
    unsigned short* __restrict__ xm_l, unsigned short* __restrict__ xm_u,
    float* __restrict__ xlin,
    int* __restrict__ cnt, uint2* __restrict__ rec)
{
    const int b = blockIdx.x, t = threadIdx.x;
    const int g8 = b >> 3, b7 = b & 7;
    const int q = g8 / 5, r5 = g8 % 5;

    if (r5 != 4) {
        // ---- fill role: edge-chunk h ----
        const int h = (q * 4 + r5) * 8 + b7;
        const int g = h * 256 + t;
        if (g >= 2 * N_EDGES) return;

        int i, j, conv;
        float s, v;
        if (g < N_EDGES) {
            i = lidx[g];
            j = lidx[N_EDGES + g];
            v = lval[g];
            s = ssl[j] + stl[i];
            conv = 0;
        } else {
            const int e = g - N_EDGES;
            i = uidx[e];
            j = uidx[N_EDGES + e];
            v = uval[e];
            s = ssu[j] + stu[i];
            conv = 1;
        }
        s = (s > 0.f) ? s : expm1f(s);
        const uint2 packed = make_uint2(((unsigned)j << 16) | (unsigned)f2bf(s * v),
                                       (unsigned)(i & (RANGE - 1)));
        const int bbase = (conv * NRANGE + (i >> 6)) * NSUB;
#pragma unroll 1
        for (int trial = 0; trial < NSUB; ++trial) {
            const int bkt = bbase + ((b7 + trial) & (NSUB - 1));
            const int rank = atomicAdd(&cnt[bkt], 1);
            if (rank < CAPB) {
                rec[(size_t)bkt * CAPB + rank] = packed;
                break;
            }
        }
        return;
    }

    // ---- pre role: rows pid*32 .. +31 ----
    const int pid = q * 8 + b7;
    const int lane = t & 63;
    const int wvu = __builtin_amdgcn_readfirstlane(t >> 6);
    const int row0 = pid * 32 + wvu * 8;
    if (row0 >= N_NODES) return;

    const float* xr[8];
#pragma unroll
    for (int r = 0; r < 8; ++r) {
        int rr = row0 + r;
        if (rr >= N_NODES) rr = N_NODES - 1;
        xr[r] = x + (size_t)rr * C;
    }

    float acc_l[8] = {0,0,0,0,0,0,0,0};
    float acc_u[8] = {0,0,0,0,0,0,0,0};
    float acc_n[8] = {0,0,0,0,0,0,0,0};

#pragma unroll 1
    for (int kc = 0; kc < C; kc += 4) {
#pragma unroll
        for (int kk = 0; kk < 4; ++kk) {
            const int k = kc + kk;
            const float wl = w_l[k * C + lane];
            const float wu = w_u[k * C + lane];
            const float wn = w_lin[k * C + lane];
#pragma unroll
            for (int r = 0; r < 8; ++r) {
                const float xk = xr[r][k];      // wave-uniform -> scalar load
                acc_l[r] = fmaf(xk, wl, acc_l[r]);
                acc_u[r] = fmaf(xk, wu, acc_u[r]);
                acc_n[r] = fmaf(xk, wn, acc_n[r]);
            }
        }
    }

#pragma unroll
    for (int r = 0; r < 8; ++r) {
        const int row = row0 + r;
        if (row < N_NODES) {
            xm_l[row * C + lane] = f2bf(acc_l[r]);
            xm_u[row * C + lane] = f2bf(acc_u[r]);
            xlin[row * C + lane] = acc_n[r] * EPS_F;
        }
    }
}

// ---------------------------------------------------------------------------
// Kernel 2: gather v5. One BLOCK per 64-node range; LDS accumulator
// acc[64][66] shared by BOTH convs (they sum anyway). Wave w walks
// (conv,sub) pairs w, w+4, w+8, w+12. Per batch of 8 records: sub8=lane>>3
// picks the record (uint2 broadcast-load), cg=lane&7 picks 8 channels
// (ushort8 row load = 1 VMEM per 8 records); ds_add_f32 into the target
// row. Epilogue: + xlin, ReLU, coalesced float stores.
// ---------------------------------------------------------------------------
__global__ __launch_bounds__(256) void gather_kernel(
    const float* __restrict__ xlin,
    const int* __restrict__ cnt, const uint2* __restrict__ rec,
    const unsigned short* __restrict__ xm_l, const unsigned short* __restrict__ xm_u,
    float* __restrict__ out)
{
    const int r = blockIdx.x;
    const int t = threadIdx.x;

    __shared__ float acc[RANGE * LDS_STRIDE];   // 16.5 KB
    for (int k = t; k < RANGE * LDS_STRIDE; k += 256) acc[k] = 0.f;
    __syncthreads();

    const int wv = t >> 6, lane = t & 63;
    const int sub8 = lane >> 3;     // record slot within batch
    const int cg = lane & 7;        // channel oct

#pragma unroll 1
    for (int pair = wv; pair < 2 * NSUB; pair += 4) {
        const int conv = pair >> 3;
        const int sub = pair & (NSUB - 1);
        const unsigned short* __restrict__ xm = conv ? xm_u : xm_l;
        const int bkt = (conv * NRANGE + r) * NSUB + sub;
        const int len = min(cnt[bkt], CAPB);
        const uint2* __restrict__ rb = rec + (size_t)bkt * CAPB;
#pragma unroll 1
        for (int kb = 0; kb < len; kb += 8) {
            const int idx = kb + sub8;
            const bool act = idx < len;
            const uint2 rw = rb[act ? idx : kb];     // kb < len -> valid
            const float w = act ? bf2f((unsigned short)(rw.x & 0xFFFFu)) : 0.f;
            const int j = (int)(rw.x >> 16);
            const int il = (int)(rw.y & (RANGE - 1));
            const u16x8 row = *(const u16x8*)(xm + j * C + cg * 8);
            float* dst = acc + il * LDS_STRIDE + cg * 8;
#pragma unroll
            for (int c = 0; c < 8; ++c)
                atomicAdd(&dst[c], w * bf2f(row[c]));
        }
    }

    __syncthreads();

    // epilogue: 64 nodes x 64 ch = 4096 floats, 16 per thread, coalesced
    const int base_node = r * RANGE;
#pragma unroll
    for (int rep = 0; rep < 16; ++rep) {
        const int flat = rep * 256 + t;
        const int nl = flat >> 6, ch = flat & 63;
        const int node = base_node + nl;
        if (node < N_NODES) {
            const float v = acc[nl * LDS_STRIDE + ch] + xlin[node * C + ch];
            out[node * C + ch] = fmaxf(v, 0.f);
        }
    }
}

extern "C" void kernel_launch(void* const* d_in, const int* in_sizes, int n_in,
                              void* d_out, int out_size, void* d_ws, size_t ws_size,
                              hipStream_t stream)
{
    const float* x          = (const float*)d_in[0];
    const int*   lower_idx  = (const int*)d_in[1];
    const float* lower_vals = (const float*)d_in[2];
    const int*   upper_idx  = (const int*)d_in[3];
    const float* upper_vals = (const float*)d_in[4];
    const float* w_lower    = (const float*)d_in[5];
    const float* a_lower    = (const float*)d_in[6];
    const float* w_upper    = (const float*)d_in[7];
    const float* a_upper    = (const float*)d_in[8];
    const float* w_lin      = (const float*)d_in[9];

    float* out = (float*)d_out;
    char* ws = (char*)d_ws;

    // ---- workspace layout (~52 MB) ----
    const size_t NC_F = (size_t)N_NODES * C * sizeof(float);          // 12.8 MB
    const size_t NC_H = (size_t)N_NODES * C * sizeof(unsigned short); // 6.4 MB
    unsigned short* xm_l = (unsigned short*)ws;  ws += NC_H;
    unsigned short* xm_u = (unsigned short*)ws;  ws += NC_H;
    float* xlin = (float*)ws;                 ws += NC_F;
    float* ssl  = (float*)ws;                 ws += N_NODES * sizeof(float);
    float* stl  = (float*)ws;                 ws += N_NODES * sizeof(float);
    float* ssu  = (float*)ws;                 ws += N_NODES * sizeof(float);
    float* stu  = (float*)ws;                 ws += N_NODES * sizeof(float);
    int* cnt    = (int*)ws;                   ws += (NBKT + 8) * sizeof(int);   // 50 KB
    uint2* rec  = (uint2*)ws;                 ws += (size_t)NBKT * CAPB * sizeof(uint2); // 19.2 MB

    // K0: attention scalars (wa-trick) + cnt zeroing
    s_kernel<<<NPRE, 256, 0, stream>>>(
        x, w_lower, a_lower, w_upper, a_upper,
        ssl, stl, ssu, stu, cnt);

    // K1: fused GEMM precompute + append-bucket fill
    gemm_fill_kernel<<<NK1, 256, 0, stream>>>(
        x, w_lower, w_upper, w_lin,
        lower_idx, lower_vals, upper_idx, upper_vals,
        ssl, stl, ssu, stu,
        xm_l, xm_u, xlin, cnt, rec);

    // K2: range-gather with LDS accumulation + skip + relu
    gather_kernel<<<NRANGE, 256, 0, stream>>>(
        xlin, cnt, rec, xm_l, xm_u, out);
}

// Round 13
// 871.489 us; speedup vs baseline: 1.0343x; 1.0343x over previous
//
#include <hip/hip_runtime.h>
#include <hip/hip_bf16.h>
#include <math.h>

#define N_NODES 50000
#define N_EDGES 800000
#define C 64
#define EPS_F 1.000001f

// Append buckets (round-11/12 lessons: never scatter 4-8B records into big
// slab regions — append via cursor; and never starve gather of blocks).
// Bucket key = (conv, 16-node target range, sub); sub thins same-line
// interleave; overflow cascades to the next sub (gather reads all subs ->
// exact). Per-(range,conv) records ~ Poisson(256)/8 per sub ~ 32+-6;
// CAPB=64 is ample.
#define RANGE 16
#define NRANGE (N_NODES / RANGE)                  // 3125 (exact)
#define NSUB 8
#define NBKT (2 * NRANGE * NSUB)                  // 50000 buckets
#define CAPB 64                                   // rec = 50000*64*8B = 25.6 MB
#define LDS_STRIDE 66                             // 2-way max bank aliasing (free)

#define NPRE ((N_NODES + 31) / 32)   // 1563 blocks, 32 rows each
// Fused K1 geometry: groups of 8; role by (b>>3)%5: 4 fill-groups : 1 pre.
#define NGRP8 980
#define NK1 (NGRP8 * 8)              // 7840 blocks: 6272 fill + 1568 pre

typedef __attribute__((ext_vector_type(8))) unsigned short u16x8;

// float <-> bf16 bits (round-to-nearest-even)
__device__ __forceinline__ unsigned short f2bf(float f) {
    unsigned u = __float_as_uint(f);
    return (unsigned short)((u + 0x7FFFu + ((u >> 16) & 1u)) >> 16);
}
__device__ __forceinline__ float bf2f(unsigned short b) {
    return __uint_as_float(((unsigned)b) << 16);
}

// ---------------------------------------------------------------------------
// Kernel 0: attention scalars via the wa-trick + zero cnt[].
//   s_src = (x @ W) @ a_src = x @ (W @ a_src)
// ---------------------------------------------------------------------------
__global__ __launch_bounds__(256) void s_kernel(
    const float* __restrict__ x,
    const float* __restrict__ w_l, const float* __restrict__ a_l,
    const float* __restrict__ w_u, const float* __restrict__ a_u,
    float* __restrict__ ssl, float* __restrict__ stl,
    float* __restrict__ ssu, float* __restrict__ stu,
    int* __restrict__ cnt)
{
    const int b = blockIdx.x;
    const int t = threadIdx.x;

    const int gz = b * 256 + t;
    if (gz < NBKT + 8) cnt[gz] = 0;

    __shared__ float wa[4 * C];      // [l_src | l_tgt | u_src | u_tgt]
    {
        const int v = t >> 6;
        const int k = t & 63;
        const float* __restrict__ w = (v < 2) ? w_l : w_u;
        const float* __restrict__ a = (v < 2) ? a_l : a_u;
        const int ao = (v & 1) * C;
        float acc = 0.f;
#pragma unroll 16
        for (int o = 0; o < C; ++o)
            acc = fmaf(w[k * C + o], a[ao + o], acc);
        wa[v * C + k] = acc;
    }
    __syncthreads();

    const int lane = t & 63;
    const int wv = t >> 6;
    const int row0 = b * 32 + wv * 8;
    if (row0 >= N_NODES) return;

    const float wls = wa[lane], wlt = wa[C + lane];
    const float wus = wa[2 * C + lane], wut = wa[3 * C + lane];

#pragma unroll
    for (int r = 0; r < 8; ++r) {
        const int row = row0 + r;
        if (row >= N_NODES) break;
        const float xv = x[row * C + lane];
        float psl = xv * wls, ptl = xv * wlt;
        float psu = xv * wus, ptu = xv * wut;
#pragma unroll
        for (int o = 32; o >= 1; o >>= 1) {
            psl += __shfl_xor(psl, o);
            ptl += __shfl_xor(ptl, o);
            psu += __shfl_xor(psu, o);
            ptu += __shfl_xor(ptu, o);
        }
        if (lane == 0) {
            ssl[row] = psl; stl[row] = ptl;
            ssu[row] = psu; stu[row] = ptu;
        }
    }
}

// ---------------------------------------------------------------------------
// Kernel 1 (fused): GEMM precompute + append-bucket fill (no grid barrier).
// Fill: alpha = elu(s_src[j]+s_tgt[i])*val; append {j|alpha, i&15} to
// bucket (conv, i>>4, sub); cascade subs on overflow.
// Pre: 8 rows/wave, wave-uniform row ptrs -> scalar x loads.
// ---------------------------------------------------------------------------
__global__ __launch_bounds__(256) void gemm_fill_kernel(
    const float* __restrict__ x,
    const float* __restrict__ w_l, const float* __restrict__ w_u,
    const float* __restrict__ w_lin,
    const int* __restrict__ lidx, const float* __restrict__ lval,
    const int* __restrict__ uidx, const float* __restrict__ uval,
    const float* __restrict__ ssl, const float* __restrict__ stl,
    const float* __restrict__ ssu, const float* __restrict__ stu,
    unsigned short* __restrict__ xm_l, unsigned short* __restrict__ xm_u,
    float* __restrict__ xlin,
    int* __restrict__ cnt, uint2* __restrict__ rec)
{
    const int b = blockIdx.x, t = threadIdx.x;
    const int g8 = b >> 3, b7 = b & 7;
    const int q = g8 / 5, r5 = g8 % 5;

    if (r5 != 4) {
        // ---- fill role: edge-chunk h ----
        const int h = (q * 4 + r5) * 8 + b7;
        const int g = h * 256 + t;
        if (g >= 2 * N_EDGES) return;

        int i, j, conv;
        float s, v;
        if (g < N_EDGES) {
            i = lidx[g];
            j = lidx[N_EDGES + g];
            v = lval[g];
            s = ssl[j] + stl[i];
            conv = 0;
        } else {
            const int e = g - N_EDGES;
            i = uidx[e];
            j = uidx[N_EDGES + e];
            v = uval[e];
            s = ssu[j] + stu[i];
            conv = 1;
        }
        s = (s > 0.f) ? s : expm1f(s);
        const uint2 packed = make_uint2(((unsigned)j << 16) | (unsigned)f2bf(s * v),
                                       (unsigned)(i & (RANGE - 1)));
        const int bbase = (conv * NRANGE + (i >> 4)) * NSUB;
#pragma unroll 1
        for (int trial = 0; trial < NSUB; ++trial) {
            const int bkt = bbase + ((b7 + trial) & (NSUB - 1));
            const int rank = atomicAdd(&cnt[bkt], 1);
            if (rank < CAPB) {
                rec[(size_t)bkt * CAPB + rank] = packed;
                break;
            }
        }
        return;
    }

    // ---- pre role: rows pid*32 .. +31 ----
    const int pid = q * 8 + b7;
    const int lane = t & 63;
    const int wvu = __builtin_amdgcn_readfirstlane(t >> 6);
    const int row0 = pid * 32 + wvu * 8;
    if (row0 >= N_NODES) return;

    const float* xr[8];
#pragma unroll
    for (int r = 0; r < 8; ++r) {
        int rr = row0 + r;
        if (rr >= N_NODES) rr = N_NODES - 1;
        xr[r] = x + (size_t)rr * C;
    }

    float acc_l[8] = {0,0,0,0,0,0,0,0};
    float acc_u[8] = {0,0,0,0,0,0,0,0};
    float acc_n[8] = {0,0,0,0,0,0,0,0};

#pragma unroll 1
    for (int kc = 0; kc < C; kc += 4) {
#pragma unroll
        for (int kk = 0; kk < 4; ++kk) {
            const int k = kc + kk;
            const float wl = w_l[k * C + lane];
            const float wu = w_u[k * C + lane];
            const float wn = w_lin[k * C + lane];
#pragma unroll
            for (int r = 0; r < 8; ++r) {
                const float xk = xr[r][k];      // wave-uniform -> scalar load
                acc_l[r] = fmaf(xk, wl, acc_l[r]);
                acc_u[r] = fmaf(xk, wu, acc_u[r]);
                acc_n[r] = fmaf(xk, wn, acc_n[r]);
            }
        }
    }

#pragma unroll
    for (int r = 0; r < 8; ++r) {
        const int row = row0 + r;
        if (row < N_NODES) {
            xm_l[row * C + lane] = f2bf(acc_l[r]);
            xm_u[row * C + lane] = f2bf(acc_u[r]);
            xlin[row * C + lane] = acc_n[r] * EPS_F;
        }
    }
}

// ---------------------------------------------------------------------------
// Kernel 2: gather v6. One BLOCK per 16-node range; 4.2 KB LDS accumulator
// acc[16][66] shared by both convs. Wave w walks sub pairs {w, w+4}; for each
// sub it processes the conv-0 and conv-1 buckets with INTERLEAVED cursors
// (two independent rec->row->ds_add chains in flight). Batch of 8 records:
// sub8 = lane>>3 picks the record, cg = lane&7 picks 8 channels (16 B row
// load). Epilogue: + xlin, ReLU, coalesced stores.
// ---------------------------------------------------------------------------
__global__ __launch_bounds__(256) void gather_kernel(
    const float* __restrict__ xlin,
    const int* __restrict__ cnt, const uint2* __restrict__ rec,
    const unsigned short* __restrict__ xm_l, const unsigned short* __restrict__ xm_u,
    float* __restrict__ out)
{
    const int r = blockIdx.x;
    const int t = threadIdx.x;

    __shared__ float acc[RANGE * LDS_STRIDE];   // 4.2 KB
    for (int k = t; k < RANGE * LDS_STRIDE; k += 256) acc[k] = 0.f;
    __syncthreads();

    const int wv = t >> 6, lane = t & 63;
    const int sub8 = lane >> 3;     // record slot within batch
    const int cg = lane & 7;        // channel oct

#pragma unroll
    for (int d = 0; d < 2; ++d) {
        const int sub = wv + d * 4;                       // 0..7
        const int bA = (0 * NRANGE + r) * NSUB + sub;     // conv 0
        const int bB = (1 * NRANGE + r) * NSUB + sub;     // conv 1
        const int lenA = min(cnt[bA], CAPB);
        const int lenB = min(cnt[bB], CAPB);
        const uint2* __restrict__ rbA = rec + (size_t)bA * CAPB;
        const uint2* __restrict__ rbB = rec + (size_t)bB * CAPB;

        int kA = 0, kB = 0;
        while ((kA < lenA) | (kB < lenB)) {
            const int iA = kA + sub8, iB = kB + sub8;
            const bool aA = iA < lenA, aB = iB < lenB;
            const uint2 rwA = rbA[aA ? iA : 0];
            const uint2 rwB = rbB[aB ? iB : 0];
            const int jA = aA ? (int)(rwA.x >> 16) : 0;
            const int jB = aB ? (int)(rwB.x >> 16) : 0;
            const float wA = aA ? bf2f((unsigned short)(rwA.x & 0xFFFFu)) : 0.f;
            const float wB = aB ? bf2f((unsigned short)(rwB.x & 0xFFFFu)) : 0.f;
            const int ilA = (int)(rwA.y & (RANGE - 1));
            const int ilB = (int)(rwB.y & (RANGE - 1));
            const u16x8 rowA = *(const u16x8*)(xm_l + jA * C + cg * 8);
            const u16x8 rowB = *(const u16x8*)(xm_u + jB * C + cg * 8);
            float* dA = acc + ilA * LDS_STRIDE + cg * 8;
            float* dB = acc + ilB * LDS_STRIDE + cg * 8;
#pragma unroll
            for (int c = 0; c < 8; ++c)
                atomicAdd(&dA[c], wA * bf2f(rowA[c]));
#pragma unroll
            for (int c = 0; c < 8; ++c)
                atomicAdd(&dB[c], wB * bf2f(rowB[c]));
            kA += (kA < lenA) ? 8 : 0;
            kB += (kB < lenB) ? 8 : 0;
        }
    }

    __syncthreads();

    // epilogue: 16 nodes x 64 ch = 1024 floats, 4 per thread, coalesced
    const int base_node = r * RANGE;
#pragma unroll
    for (int rep = 0; rep < 4; ++rep) {
        const int flat = rep * 256 + t;
        const int nl = flat >> 6, ch = flat & 63;
        const int node = base_node + nl;
        const float v = acc[nl * LDS_STRIDE + ch] + xlin[node * C + ch];
        out[node * C + ch] = fmaxf(v, 0.f);
    }
}

extern "C" void kernel_launch(void* const* d_in, const int* in_sizes, int n_in,
                              void* d_out, int out_size, void* d_ws, size_t ws_size,
                              hipStream_t stream)
{
    const float* x          = (const float*)d_in[0];
    const int*   lower_idx  = (const int*)d_in[1];
    const float* lower_vals = (const float*)d_in[2];
    const int*   upper_idx  = (const int*)d_in[3];
    const float* upper_vals = (const float*)d_in[4];
    const float* w_lower    = (const float*)d_in[5];
    const float* a_lower    = (const float*)d_in[6];
    const float* w_upper    = (const float*)d_in[7];
    const float* a_upper    = (const float*)d_in[8];
    const float* w_lin      = (const float*)d_in[9];

    float* out = (float*)d_out;
    char* ws = (char*)d_ws;

    // ---- workspace layout (~58 MB) ----
    const size_t NC_F = (size_t)N_NODES * C * sizeof(float);          // 12.8 MB
    const size_t NC_H = (size_t)N_NODES * C * sizeof(unsigned short); // 6.4 MB
    unsigned short* xm_l = (unsigned short*)ws;  ws += NC_H;
    unsigned short* xm_u = (unsigned short*)ws;  ws += NC_H;
    float* xlin = (float*)ws;                 ws += NC_F;
    float* ssl  = (float*)ws;                 ws += N_NODES * sizeof(float);
    float* stl  = (float*)ws;                 ws += N_NODES * sizeof(float);
    float* ssu  = (float*)ws;                 ws += N_NODES * sizeof(float);
    float* stu  = (float*)ws;                 ws += N_NODES * sizeof(float);
    int* cnt    = (int*)ws;                   ws += (NBKT + 8) * sizeof(int);   // 200 KB
    uint2* rec  = (uint2*)ws;                 ws += (size_t)NBKT * CAPB * sizeof(uint2); // 25.6 MB

    // K0: attention scalars (wa-trick) + cnt zeroing
    s_kernel<<<NPRE, 256, 0, stream>>>(
        x, w_lower, a_lower, w_upper, a_upper,
        ssl, stl, ssu, stu, cnt);

    // K1: fused GEMM precompute + append-bucket fill
    gemm_fill_kernel<<<NK1, 256, 0, stream>>>(
        x, w_lower, w_upper, w_lin,
        lower_idx, lower_vals, upper_idx, upper_vals,
        ssl, stl, ssu, stu,
        xm_l, xm_u, xlin, cnt, rec);

    // K2: range-gather with LDS accumulation + skip + relu
    gather_kernel<<<NRANGE, 256, 0, stream>>>(
        xlin, cnt, rec, xm_l, xm_u, out);
}

// Round 14
// 246.329 us; speedup vs baseline: 3.6594x; 3.5379x over previous
//
#include <hip/hip_runtime.h>
#include <hip/hip_bf16.h>
#include <math.h>

#define N_NODES 50000
#define N_EDGES 800000
#define C 64
#define EPS_F 1.000001f

// Append buckets (round-11/12 lessons: never scatter small records into big
// slab regions; append via cursor). Bucket key = (conv, 16-node range, sub).
// Overflow cascades to the next sub (gather reads all subs -> exact).
#define RANGE 16
#define NRANGE (N_NODES / RANGE)                  // 3125 (exact)
#define NSUB 8
#define NBKT (2 * NRANGE * NSUB)                  // 50000 buckets
#define CAPB 64                                   // rec = 25.6 MB
#define LDS_STRIDE 66

// Gather v7 (round-13 lesson: LDS *float* atomics are ~7x poison — CAS-loop
// lowering + same-address collision retry chains; occupancy-invariant.
// Only INT ds_add cursors allowed; float accumulation stays in registers.)
#define LCAP 80                    // per-(conv,node) LDS list capacity
                                   // deg ~ Poisson(16); P(max over 100K > 45) ~ 1e-4

#define NPRE ((N_NODES + 31) / 32)   // 1563 blocks, 32 rows each
#define NGRP8 980
#define NK1 (NGRP8 * 8)              // 7840 blocks: 6272 fill + 1568 pre

typedef __attribute__((ext_vector_type(8))) unsigned short u16x8;

__device__ __forceinline__ unsigned short f2bf(float f) {
    unsigned u = __float_as_uint(f);
    return (unsigned short)((u + 0x7FFFu + ((u >> 16) & 1u)) >> 16);
}
__device__ __forceinline__ float bf2f(unsigned short b) {
    return __uint_as_float(((unsigned)b) << 16);
}

// ---------------------------------------------------------------------------
// Kernel 0: attention scalars via the wa-trick + zero cnt[].
//   s_src = (x @ W) @ a_src = x @ (W @ a_src)
// ---------------------------------------------------------------------------
__global__ __launch_bounds__(256) void s_kernel(
    const float* __restrict__ x,
    const float* __restrict__ w_l, const float* __restrict__ a_l,
    const float* __restrict__ w_u, const float* __restrict__ a_u,
    float* __restrict__ ssl, float* __restrict__ stl,
    float* __restrict__ ssu, float* __restrict__ stu,
    int* __restrict__ cnt)
{
    const int b = blockIdx.x;
    const int t = threadIdx.x;

    const int gz = b * 256 + t;
    if (gz < NBKT + 8) cnt[gz] = 0;

    __shared__ float wa[4 * C];      // [l_src | l_tgt | u_src | u_tgt]
    {
        const int v = t >> 6;
        const int k = t & 63;
        const float* __restrict__ w = (v < 2) ? w_l : w_u;
        const float* __restrict__ a = (v < 2) ? a_l : a_u;
        const int ao = (v & 1) * C;
        float acc = 0.f;
#pragma unroll 16
        for (int o = 0; o < C; ++o)
            acc = fmaf(w[k * C + o], a[ao + o], acc);
        wa[v * C + k] = acc;
    }
    __syncthreads();

    const int lane = t & 63;
    const int wv = t >> 6;
    const int row0 = b * 32 + wv * 8;
    if (row0 >= N_NODES) return;

    const float wls = wa[lane], wlt = wa[C + lane];
    const float wus = wa[2 * C + lane], wut = wa[3 * C + lane];

#pragma unroll
    for (int r = 0; r < 8; ++r) {
        const int row = row0 + r;
        if (row >= N_NODES) break;
        const float xv = x[row * C + lane];
        float psl = xv * wls, ptl = xv * wlt;
        float psu = xv * wus, ptu = xv * wut;
#pragma unroll
        for (int o = 32; o >= 1; o >>= 1) {
            psl += __shfl_xor(psl, o);
            ptl += __shfl_xor(ptl, o);
            psu += __shfl_xor(psu, o);
            ptu += __shfl_xor(ptu, o);
        }
        if (lane == 0) {
            ssl[row] = psl; stl[row] = ptl;
            ssu[row] = psu; stu[row] = ptu;
        }
    }
}

// ---------------------------------------------------------------------------
// Kernel 1 (fused): GEMM precompute + append-bucket fill (no grid barrier).
// Unchanged from round 13.
// ---------------------------------------------------------------------------
__global__ __launch_bounds__(256) void gemm_fill_kernel(
    const float* __restrict__ x,
    const float* __restrict__ w_l, const float* __restrict__ w_u,
    const float* __restrict__ w_lin,
    const int* __restrict__ lidx, const float* __restrict__ lval,
    const int* __restrict__ uidx, const float* __restrict__ uval,
    const float* __restrict__ ssl, const float* __restrict__ stl,
    const float* __restrict__ ssu, const float* __restrict__ stu,
    unsigned short* __restrict__ xm_l, unsigned short* __restrict__ xm_u,
    float* __restrict__ xlin,
    int* __restrict__ cnt, uint2* __restrict__ rec)
{
    const int b = blockIdx.x, t = threadIdx.x;
    const int g8 = b >> 3, b7 = b & 7;
    const int q = g8 / 5, r5 = g8 % 5;

    if (r5 != 4) {
        const int h = (q * 4 + r5) * 8 + b7;
        const int g = h * 256 + t;
        if (g >= 2 * N_EDGES) return;

        int i, j, conv;
        float s, v;
        if (g < N_EDGES) {
            i = lidx[g];
            j = lidx[N_EDGES + g];
            v = lval[g];
            s = ssl[j] + stl[i];
            conv = 0;
        } else {
            const int e = g - N_EDGES;
            i = uidx[e];
            j = uidx[N_EDGES + e];
            v = uval[e];
            s = ssu[j] + stu[i];
            conv = 1;
        }
        s = (s > 0.f) ? s : expm1f(s);
        const uint2 packed = make_uint2(((unsigned)j << 16) | (unsigned)f2bf(s * v),
                                       (unsigned)(i & (RANGE - 1)));
        const int bbase = (conv * NRANGE + (i >> 4)) * NSUB;
#pragma unroll 1
        for (int trial = 0; trial < NSUB; ++trial) {
            const int bkt = bbase + ((b7 + trial) & (NSUB - 1));
            const int rank = atomicAdd(&cnt[bkt], 1);
            if (rank < CAPB) {
                rec[(size_t)bkt * CAPB + rank] = packed;
                break;
            }
        }
        return;
    }

    // ---- pre role ----
    const int pid = q * 8 + b7;
    const int lane = t & 63;
    const int wvu = __builtin_amdgcn_readfirstlane(t >> 6);
    const int row0 = pid * 32 + wvu * 8;
    if (row0 >= N_NODES) return;

    const float* xr[8];
#pragma unroll
    for (int r = 0; r < 8; ++r) {
        int rr = row0 + r;
        if (rr >= N_NODES) rr = N_NODES - 1;
        xr[r] = x + (size_t)rr * C;
    }

    float acc_l[8] = {0,0,0,0,0,0,0,0};
    float acc_u[8] = {0,0,0,0,0,0,0,0};
    float acc_n[8] = {0,0,0,0,0,0,0,0};

#pragma unroll 1
    for (int kc = 0; kc < C; kc += 4) {
#pragma unroll
        for (int kk = 0; kk < 4; ++kk) {
            const int k = kc + kk;
            const float wl = w_l[k * C + lane];
            const float wu = w_u[k * C + lane];
            const float wn = w_lin[k * C + lane];
#pragma unroll
            for (int r = 0; r < 8; ++r) {
                const float xk = xr[r][k];
                acc_l[r] = fmaf(xk, wl, acc_l[r]);
                acc_u[r] = fmaf(xk, wu, acc_u[r]);
                acc_n[r] = fmaf(xk, wn, acc_n[r]);
            }
        }
    }

#pragma unroll
    for (int r = 0; r < 8; ++r) {
        const int row = row0 + r;
        if (row < N_NODES) {
            xm_l[row * C + lane] = f2bf(acc_l[r]);
            xm_u[row * C + lane] = f2bf(acc_u[r]);
            xlin[row * C + lane] = acc_n[r] * EPS_F;
        }
    }
}

// ---------------------------------------------------------------------------
// Kernel 2: gather v7. One BLOCK per 16-node range.
// Phase A: route the range's records (16 buckets) into per-(conv,node) LDS
//          lists — INT ds_add cursors only (4 B records: j<<16 | bf16 alpha).
// Phase B: wave w owns nodes w*4..w*4+3; per (node,conv) batches of 8:
//          sub8 = lane>>3 picks record, cg = lane&7 picks 8 channels
//          (16 B u16x8 row load); FMA into 8 VGPRs; xor-shuffle reduce;
//          result rows staged in LDS; coalesced +xlin+ReLU epilogue.
// ---------------------------------------------------------------------------
__global__ __launch_bounds__(256) void gather_kernel(
    const float* __restrict__ xlin,
    const int* __restrict__ cnt, const uint2* __restrict__ rec,
    const unsigned short* __restrict__ xm_l, const unsigned short* __restrict__ xm_u,
    float* __restrict__ out)
{
    const int r = blockIdx.x;
    const int t = threadIdx.x;

    __shared__ int lcnt[2 * RANGE];                 // per-(conv,node) counts
    __shared__ unsigned lists[2 * RANGE * LCAP];    // 10 KB: routed records
    __shared__ float racc[RANGE * LDS_STRIDE];      // 4.2 KB: result tile

    if (t < 2 * RANGE) lcnt[t] = 0;
    __syncthreads();

    // ---- Phase A: route records into per-(conv,node) lists ----
#pragma unroll 1
    for (int bk = 0; bk < 2 * NSUB; ++bk) {
        const int conv = bk >> 3, sub = bk & 7;
        const int bkt = (conv * NRANGE + r) * NSUB + sub;
        const int len = min(cnt[bkt], CAPB);
        const uint2* __restrict__ rb = rec + (size_t)bkt * CAPB;
        for (int idx = t; idx < len; idx += 256) {
            const uint2 rw = rb[idx];
            const int il = (int)(rw.y & (RANGE - 1));
            const int key = conv * RANGE + il;
            const int pos = atomicAdd(&lcnt[key], 1);   // int ds_add: native
            if (pos < LCAP) lists[key * LCAP + pos] = rw.x;
        }
    }
    __syncthreads();

    // ---- Phase B: register-accumulating per-node gather ----
    const int wv = t >> 6, lane = t & 63;
    const int sub8 = lane >> 3;
    const int cg = lane & 7;

#pragma unroll 1
    for (int nsel = 0; nsel < 4; ++nsel) {
        const int nl = wv * 4 + nsel;
        float acc[8] = {0.f,0.f,0.f,0.f,0.f,0.f,0.f,0.f};
#pragma unroll
        for (int conv = 0; conv < 2; ++conv) {
            const unsigned short* __restrict__ xm = conv ? xm_u : xm_l;
            const int key = conv * RANGE + nl;
            const int len = min(lcnt[key], LCAP);
            const unsigned* __restrict__ lp = lists + key * LCAP;
#pragma unroll 1
            for (int k = 0; k < len; k += 8) {
                const int idx = k + sub8;
                const bool act = idx < len;
                const unsigned rw = lp[act ? idx : k];
                const int j = (int)(rw >> 16);
                const float w = act ? bf2f((unsigned short)(rw & 0xFFFFu)) : 0.f;
                const u16x8 row = *(const u16x8*)(xm + j * C + cg * 8);
#pragma unroll
                for (int c = 0; c < 8; ++c)
                    acc[c] = fmaf(w, bf2f(row[c]), acc[c]);
            }
        }
        // reduce over the 8 record slots (lane bits 3..5)
#pragma unroll
        for (int o = 8; o <= 32; o <<= 1)
#pragma unroll
            for (int c = 0; c < 8; ++c)
                acc[c] += __shfl_xor(acc[c], o);
        if (lane < 8) {
#pragma unroll
            for (int c = 0; c < 8; ++c)
                racc[nl * LDS_STRIDE + lane * 8 + c] = acc[c];
        }
    }
    __syncthreads();

    // ---- epilogue: 16 nodes x 64 ch, coalesced ----
    const int base_node = r * RANGE;
#pragma unroll
    for (int rep = 0; rep < 4; ++rep) {
        const int flat = rep * 256 + t;
        const int nl = flat >> 6, ch = flat & 63;
        const int node = base_node + nl;
        const float v = racc[nl * LDS_STRIDE + ch] + xlin[node * C + ch];
        out[node * C + ch] = fmaxf(v, 0.f);
    }
}

extern "C" void kernel_launch(void* const* d_in, const int* in_sizes, int n_in,
                              void* d_out, int out_size, void* d_ws, size_t ws_size,
                              hipStream_t stream)
{
    const float* x          = (const float*)d_in[0];
    const int*   lower_idx  = (const int*)d_in[1];
    const float* lower_vals = (const float*)d_in[2];
    const int*   upper_idx  = (const int*)d_in[3];
    const float* upper_vals = (const float*)d_in[4];
    const float* w_lower    = (const float*)d_in[5];
    const float* a_lower    = (const float*)d_in[6];
    const float* w_upper    = (const float*)d_in[7];
    const float* a_upper    = (const float*)d_in[8];
    const float* w_lin      = (const float*)d_in[9];

    float* out = (float*)d_out;
    char* ws = (char*)d_ws;

    // ---- workspace layout (~58 MB) ----
    const size_t NC_F = (size_t)N_NODES * C * sizeof(float);
    const size_t NC_H = (size_t)N_NODES * C * sizeof(unsigned short);
    unsigned short* xm_l = (unsigned short*)ws;  ws += NC_H;
    unsigned short* xm_u = (unsigned short*)ws;  ws += NC_H;
    float* xlin = (float*)ws;                 ws += NC_F;
    float* ssl  = (float*)ws;                 ws += N_NODES * sizeof(float);
    float* stl  = (float*)ws;                 ws += N_NODES * sizeof(float);
    float* ssu  = (float*)ws;                 ws += N_NODES * sizeof(float);
    float* stu  = (float*)ws;                 ws += N_NODES * sizeof(float);
    int* cnt    = (int*)ws;                   ws += (NBKT + 8) * sizeof(int);
    uint2* rec  = (uint2*)ws;                 ws += (size_t)NBKT * CAPB * sizeof(uint2);

    // K0: attention scalars (wa-trick) + cnt zeroing
    s_kernel<<<NPRE, 256, 0, stream>>>(
        x, w_lower, a_lower, w_upper, a_upper,
        ssl, stl, ssu, stu, cnt);

    // K1: fused GEMM precompute + append-bucket fill
    gemm_fill_kernel<<<NK1, 256, 0, stream>>>(
        x, w_lower, w_upper, w_lin,
        lower_idx, lower_vals, upper_idx, upper_vals,
        ssl, stl, ssu, stu,
        xm_l, xm_u, xlin, cnt, rec);

    // K2: gather v7 (LDS routing + register accumulation) + skip + relu
    gather_kernel<<<NRANGE, 256, 0, stream>>>(
        xlin, cnt, rec, xm_l, xm_u, out);
}

// Round 15
// 229.233 us; speedup vs baseline: 3.9323x; 1.0746x over previous
//
#include <hip/hip_runtime.h>
#include <hip/hip_bf16.h>
#include <math.h>

#define N_NODES 50000
#define N_EDGES 800000
#define C 64
#define EPS_F 1.000001f

// Per-(conv,node) append buckets with 4 B records {j:16 | bf16(alpha):16}.
// Round-14 evidence: fill time is INVARIANT to record-store shape (97 us at
// 126/137/94 MB written across r10/r11/r14) -> shrink records for the
// reader's benefit; the writer doesn't care. CAPN=48 slots = 192 B aligned;
// deg ~ Poisson(16), P(>48) ~ 1e-9 per bucket; exactness via a global
// overflow list that gather scans (expected empty).
#define CAPN 48
#define NCNT (2 * N_NODES)            // one cursor per (conv,node)
#define OVF_IDX NCNT                  // overflow cursor slot
#define OMAX 4096

#define RANGE 16                      // gather: nodes per block
#define NGATH (N_NODES / RANGE)       // 3125 blocks
#define LDS_STRIDE 66

#define NPRE ((N_NODES + 31) / 32)    // 1563 blocks, 32 rows each
#define NGRP8 980
#define NK1 (NGRP8 * 8)               // 7840 blocks: 6272 fill + 1568 pre

typedef __attribute__((ext_vector_type(8))) unsigned short u16x8;

__device__ __forceinline__ unsigned short f2bf(float f) {
    unsigned u = __float_as_uint(f);
    return (unsigned short)((u + 0x7FFFu + ((u >> 16) & 1u)) >> 16);
}
__device__ __forceinline__ float bf2f(unsigned short b) {
    return __uint_as_float(((unsigned)b) << 16);
}

// ---------------------------------------------------------------------------
// Kernel 0: attention scalars via the wa-trick + zero cnt[] (incl. overflow
// cursor).  s_src = (x @ W) @ a_src = x @ (W @ a_src)
// ---------------------------------------------------------------------------
__global__ __launch_bounds__(256) void s_kernel(
    const float* __restrict__ x,
    const float* __restrict__ w_l, const float* __restrict__ a_l,
    const float* __restrict__ w_u, const float* __restrict__ a_u,
    float* __restrict__ ssl, float* __restrict__ stl,
    float* __restrict__ ssu, float* __restrict__ stu,
    int* __restrict__ cnt)
{
    const int b = blockIdx.x;
    const int t = threadIdx.x;

    const int gz = b * 256 + t;
    if (gz <= OVF_IDX) cnt[gz] = 0;

    __shared__ float wa[4 * C];      // [l_src | l_tgt | u_src | u_tgt]
    {
        const int v = t >> 6;
        const int k = t & 63;
        const float* __restrict__ w = (v < 2) ? w_l : w_u;
        const float* __restrict__ a = (v < 2) ? a_l : a_u;
        const int ao = (v & 1) * C;
        float acc = 0.f;
#pragma unroll 16
        for (int o = 0; o < C; ++o)
            acc = fmaf(w[k * C + o], a[ao + o], acc);
        wa[v * C + k] = acc;
    }
    __syncthreads();

    const int lane = t & 63;
    const int wv = t >> 6;
    const int row0 = b * 32 + wv * 8;
    if (row0 >= N_NODES) return;

    const float wls = wa[lane], wlt = wa[C + lane];
    const float wus = wa[2 * C + lane], wut = wa[3 * C + lane];

#pragma unroll
    for (int r = 0; r < 8; ++r) {
        const int row = row0 + r;
        if (row >= N_NODES) break;
        const float xv = x[row * C + lane];
        float psl = xv * wls, ptl = xv * wlt;
        float psu = xv * wus, ptu = xv * wut;
#pragma unroll
        for (int o = 32; o >= 1; o >>= 1) {
            psl += __shfl_xor(psl, o);
            ptl += __shfl_xor(ptl, o);
            psu += __shfl_xor(psu, o);
            ptu += __shfl_xor(ptu, o);
        }
        if (lane == 0) {
            ssl[row] = psl; stl[row] = ptl;
            ssu[row] = psu; stu[row] = ptu;
        }
    }
}

// ---------------------------------------------------------------------------
// Kernel 1 (fused): GEMM precompute + per-node append fill (no grid barrier).
// Fill: alpha = elu(s_src[j]+s_tgt[i])*val; bucket = conv*N + i;
// rank = atomicAdd(cnt[bucket]); rec[bucket*CAPN+rank] = {j|alpha};
// rank >= CAPN (never, statistically) -> global overflow list.
// Pre: 8 rows/wave, wave-uniform row ptrs -> scalar x loads.
// ---------------------------------------------------------------------------
__global__ __launch_bounds__(256) void gemm_fill_kernel(
    const float* __restrict__ x,
    const float* __restrict__ w_l, const float* __restrict__ w_u,
    const float* __restrict__ w_lin,
    const int* __restrict__ lidx, const float* __restrict__ lval,
    const int* __restrict__ uidx, const float* __restrict__ uval,
    const float* __restrict__ ssl, const float* __restrict__ stl,
    const float* __restrict__ ssu, const float* __restrict__ stu,
    unsigned short* __restrict__ xm_l, unsigned short* __restrict__ xm_u,
    float* __restrict__ xlin,
    int* __restrict__ cnt, unsigned* __restrict__ rec, int2* __restrict__ ovf)
{
    const int b = blockIdx.x, t = threadIdx.x;
    const int g8 = b >> 3, b7 = b & 7;
    const int q = g8 / 5, r5 = g8 % 5;

    if (r5 != 4) {
        // ---- fill role: edge-chunk h ----
        const int h = (q * 4 + r5) * 8 + b7;
        const int g = h * 256 + t;
        if (g >= 2 * N_EDGES) return;

        int i, j, conv;
        float s, v;
        if (g < N_EDGES) {
            i = lidx[g];
            j = lidx[N_EDGES + g];
            v = lval[g];
            s = ssl[j] + stl[i];
            conv = 0;
        } else {
            const int e = g - N_EDGES;
            i = uidx[e];
            j = uidx[N_EDGES + e];
            v = uval[e];
            s = ssu[j] + stu[i];
            conv = 1;
        }
        s = (s > 0.f) ? s : expm1f(s);
        const unsigned packed = ((unsigned)j << 16) | (unsigned)f2bf(s * v);
        const int bucket = conv * N_NODES + i;
        const int rank = atomicAdd(&cnt[bucket], 1);
        if (rank < CAPN) {
            rec[(size_t)bucket * CAPN + rank] = packed;
        } else {
            const int oi = atomicAdd(&cnt[OVF_IDX], 1);
            if (oi < OMAX) ovf[oi] = make_int2(bucket, (int)packed);
        }
        return;
    }

    // ---- pre role: rows pid*32 .. +31 ----
    const int pid = q * 8 + b7;
    const int lane = t & 63;
    const int wvu = __builtin_amdgcn_readfirstlane(t >> 6);
    const int row0 = pid * 32 + wvu * 8;
    if (row0 >= N_NODES) return;

    const float* xr[8];
#pragma unroll
    for (int r = 0; r < 8; ++r) {
        int rr = row0 + r;
        if (rr >= N_NODES) rr = N_NODES - 1;
        xr[r] = x + (size_t)rr * C;
    }

    float acc_l[8] = {0,0,0,0,0,0,0,0};
    float acc_u[8] = {0,0,0,0,0,0,0,0};
    float acc_n[8] = {0,0,0,0,0,0,0,0};

#pragma unroll 1
    for (int kc = 0; kc < C; kc += 4) {
#pragma unroll
        for (int kk = 0; kk < 4; ++kk) {
            const int k = kc + kk;
            const float wl = w_l[k * C + lane];
            const float wu = w_u[k * C + lane];
            const float wn = w_lin[k * C + lane];
#pragma unroll
            for (int r = 0; r < 8; ++r) {
                const float xk = xr[r][k];      // wave-uniform -> scalar load
                acc_l[r] = fmaf(xk, wl, acc_l[r]);
                acc_u[r] = fmaf(xk, wu, acc_u[r]);
                acc_n[r] = fmaf(xk, wn, acc_n[r]);
            }
        }
    }

#pragma unroll
    for (int r = 0; r < 8; ++r) {
        const int row = row0 + r;
        if (row < N_NODES) {
            xm_l[row * C + lane] = f2bf(acc_l[r]);
            xm_u[row * C + lane] = f2bf(acc_u[r]);
            xlin[row * C + lane] = acc_n[r] * EPS_F;
        }
    }
}

// ---------------------------------------------------------------------------
// Kernel 2: gather v8 — per-node lists read directly (Phase A deleted).
// One BLOCK per 16 nodes; wave w owns nodes w*4..w*4+3. Per node the conv-0
// and conv-1 lists are walked with INTERLEAVED cursors (two independent
// rec->row->fma chains). Batch of 8: sub8 = lane>>3 picks the record,
// cg = lane&7 picks 8 channels (16 B u16x8 row load = 1 VMEM / 8 records).
// Register accumulation (round-13 lesson: no LDS float atomics), xor-shuffle
// reduce, LDS-staged coalesced epilogue (+xlin, ReLU).
// ---------------------------------------------------------------------------
__global__ __launch_bounds__(256) void gather_kernel(
    const float* __restrict__ xlin,
    const int* __restrict__ cnt, const unsigned* __restrict__ rec,
    const int2* __restrict__ ovf,
    const unsigned short* __restrict__ xm_l, const unsigned short* __restrict__ xm_u,
    float* __restrict__ out)
{
    const int r = blockIdx.x;
    const int t = threadIdx.x;
    const int wv = t >> 6, lane = t & 63;
    const int sub8 = lane >> 3;
    const int cg = lane & 7;

    __shared__ float racc[RANGE * LDS_STRIDE];   // 4.2 KB result tile

    const int oc = min(cnt[OVF_IDX], OMAX);

#pragma unroll 1
    for (int nsel = 0; nsel < 4; ++nsel) {
        const int node = r * RANGE + wv * 4 + nsel;
        const int bA = node;               // conv 0
        const int bB = N_NODES + node;     // conv 1
        const int lenA = min(cnt[bA], CAPN);
        const int lenB = min(cnt[bB], CAPN);
        const unsigned* __restrict__ rbA = rec + (size_t)bA * CAPN;
        const unsigned* __restrict__ rbB = rec + (size_t)bB * CAPN;

        float acc[8] = {0.f,0.f,0.f,0.f,0.f,0.f,0.f,0.f};
        int kA = 0, kB = 0;
        while ((kA < lenA) | (kB < lenB)) {
            const int iA = kA + sub8, iB = kB + sub8;
            const bool aA = iA < lenA, aB = iB < lenB;
            const unsigned rwA = rbA[aA ? iA : kA];   // kA valid when aA possible
            const unsigned rwB = rbB[aB ? iB : kB];
            const int jA = aA ? (int)(rwA >> 16) : 0;
            const int jB = aB ? (int)(rwB >> 16) : 0;
            const float wA = aA ? bf2f((unsigned short)(rwA & 0xFFFFu)) : 0.f;
            const float wB = aB ? bf2f((unsigned short)(rwB & 0xFFFFu)) : 0.f;
            const u16x8 rowA = *(const u16x8*)(xm_l + jA * C + cg * 8);
            const u16x8 rowB = *(const u16x8*)(xm_u + jB * C + cg * 8);
#pragma unroll
            for (int c = 0; c < 8; ++c)
                acc[c] = fmaf(wA, bf2f(rowA[c]), acc[c]);
#pragma unroll
            for (int c = 0; c < 8; ++c)
                acc[c] = fmaf(wB, bf2f(rowB[c]), acc[c]);
            kA += (kA < lenA) ? 8 : 0;
            kB += (kB < lenB) ? 8 : 0;
        }

        // overflow tail (expected empty; exact correctness for CAPN spills)
        for (int u = 0; u < oc; ++u) {
            const int2 e = ovf[u];
            if (e.x == bA || e.x == bB) {
                const unsigned rw = (unsigned)e.y;
                const int j = (int)(rw >> 16);
                const float w = (sub8 == 0) ? bf2f((unsigned short)(rw & 0xFFFFu)) : 0.f;
                const unsigned short* xm = (e.x == bA) ? xm_l : xm_u;
                const u16x8 row = *(const u16x8*)(xm + j * C + cg * 8);
#pragma unroll
                for (int c = 0; c < 8; ++c)
                    acc[c] = fmaf(w, bf2f(row[c]), acc[c]);
            }
        }

        // reduce over the 8 record slots (lane bits 3..5)
#pragma unroll
        for (int o = 8; o <= 32; o <<= 1)
#pragma unroll
            for (int c = 0; c < 8; ++c)
                acc[c] += __shfl_xor(acc[c], o);
        const int nl = wv * 4 + nsel;
        if (lane < 8) {
#pragma unroll
            for (int c = 0; c < 8; ++c)
                racc[nl * LDS_STRIDE + lane * 8 + c] = acc[c];
        }
    }
    __syncthreads();

    // epilogue: 16 nodes x 64 ch, coalesced
    const int base_node = r * RANGE;
#pragma unroll
    for (int rep = 0; rep < 4; ++rep) {
        const int flat = rep * 256 + t;
        const int nl = flat >> 6, ch = flat & 63;
        const int node = base_node + nl;
        const float v = racc[nl * LDS_STRIDE + ch] + xlin[node * C + ch];
        out[node * C + ch] = fmaxf(v, 0.f);
    }
}

extern "C" void kernel_launch(void* const* d_in, const int* in_sizes, int n_in,
                              void* d_out, int out_size, void* d_ws, size_t ws_size,
                              hipStream_t stream)
{
    const float* x          = (const float*)d_in[0];
    const int*   lower_idx  = (const int*)d_in[1];
    const float* lower_vals = (const float*)d_in[2];
    const int*   upper_idx  = (const int*)d_in[3];
    const float* upper_vals = (const float*)d_in[4];
    const float* w_lower    = (const float*)d_in[5];
    const float* a_lower    = (const float*)d_in[6];
    const float* w_upper    = (const float*)d_in[7];
    const float* a_upper    = (const float*)d_in[8];
    const float* w_lin      = (const float*)d_in[9];

    float* out = (float*)d_out;
    char* ws = (char*)d_ws;

    // ---- workspace layout (~47 MB) ----
    const size_t NC_F = (size_t)N_NODES * C * sizeof(float);
    const size_t NC_H = (size_t)N_NODES * C * sizeof(unsigned short);
    unsigned short* xm_l = (unsigned short*)ws;  ws += NC_H;
    unsigned short* xm_u = (unsigned short*)ws;  ws += NC_H;
    float* xlin = (float*)ws;                 ws += NC_F;
    float* ssl  = (float*)ws;                 ws += N_NODES * sizeof(float);
    float* stl  = (float*)ws;                 ws += N_NODES * sizeof(float);
    float* ssu  = (float*)ws;                 ws += N_NODES * sizeof(float);
    float* stu  = (float*)ws;                 ws += N_NODES * sizeof(float);
    int* cnt    = (int*)ws;                   ws += (NCNT + 16) * sizeof(int);  // 400 KB
    int2* ovf   = (int2*)ws;                  ws += OMAX * sizeof(int2);
    unsigned* rec = (unsigned*)ws;            ws += ((size_t)NCNT * CAPN + 64) * sizeof(unsigned); // 19.2 MB

    // K0: attention scalars (wa-trick) + cnt/overflow-cursor zeroing
    s_kernel<<<NPRE, 256, 0, stream>>>(
        x, w_lower, a_lower, w_upper, a_upper,
        ssl, stl, ssu, stu, cnt);

    // K1: fused GEMM precompute + per-node append fill
    gemm_fill_kernel<<<NK1, 256, 0, stream>>>(
        x, w_lower, w_upper, w_lin,
        lower_idx, lower_vals, upper_idx, upper_vals,
        ssl, stl, ssu, stu,
        xm_l, xm_u, xlin, cnt, rec, ovf);

    // K2: gather v8 (direct per-node lists) + skip + relu
    gather_kernel<<<NGATH, 256, 0, stream>>>(
        xlin, cnt, rec, ovf, xm_l, xm_u, out);
}